// Round 6
// baseline (118.077 us; speedup 1.0000x reference)
//
#include <hip/hip_runtime.h>

#define NEG 5
#define MM 6
#define NCTX 6
#define DD 128
#define WPB 4           // waves per block
#define RPW 2           // rows per wave (half-wave per row)
#define RPB (WPB * RPW)
#define DROW 12

#define SB() __builtin_amdgcn_sched_barrier(0)

__device__ __forceinline__ int geti(const int4& v, int c) {
    switch (c) { case 0: return v.x; case 1: return v.y; case 2: return v.z; default: return v.w; }
}
__device__ __forceinline__ float getf(const float4& v, int c) {
    switch (c) { case 0: return v.x; case 1: return v.y; case 2: return v.z; default: return v.w; }
}

// ================= Phase A: w = embedding-bag(emb0) =================
__global__ __launch_bounds__(256) void sg_w_kernel(
    const int*   __restrict__ w2m,        // [B,6]
    const float* __restrict__ w2m_mask,   // [B,6]
    const float* __restrict__ emb0,       // [V,128]
    float*       __restrict__ wbuf,       // [B,128]
    int B)
{
    const int lane  = threadIdx.x & 63;
    const int wid   = threadIdx.x >> 6;
    const int sub   = lane >> 5;
    const int slane = lane & 31;
    const int base  = lane & 32;
    const int b     = blockIdx.x * RPB + wid * RPW + sub;
    if (b >= B) return;

    int wi = 0; float wmk = 0.f;
    if (slane < MM)           wi  = w2m[(size_t)b * MM + slane];
    else if (slane < 2 * MM)  wmk = w2m_mask[(size_t)b * MM + (slane - MM)];

    const int d0 = slane * 4;
    float4 rr[MM]; float mk[MM];
    #pragma unroll
    for (int m = 0; m < MM; ++m) {
        const int idx = __shfl(wi, base + m, 64);
        mk[m]         = __shfl(wmk, base + MM + m, 64);
        rr[m] = *reinterpret_cast<const float4*>(emb0 + (size_t)idx * DD + d0);
    }
    float4 acc = {0.f, 0.f, 0.f, 0.f};
    #pragma unroll
    for (int m = 0; m < MM; ++m) {
        acc.x += rr[m].x * mk[m]; acc.y += rr[m].y * mk[m];
        acc.z += rr[m].z * mk[m]; acc.w += rr[m].w * mk[m];
    }
    *reinterpret_cast<float4*>(wbuf + (size_t)b * DD + d0) = acc;
}

// ================= Phase B: dots against emb1 + loss =================
template<int J>
__device__ __forceinline__ void issue_ctx(float4* dst, const int4& ci, int base,
                                          const float* __restrict__ emb1, int d0) {
    #pragma unroll
    for (int m = 0; m < MM; ++m) {
        const int flat = J * MM + m;
        const int k = flat >> 2, c = flat & 3;
        const int idx = __shfl(geti(ci, c), base + k, 64);
        dst[m] = *reinterpret_cast<const float4*>(emb1 + (size_t)idx * DD + d0);
    }
}

template<int J>
__device__ __forceinline__ float consume_dot(const float4* src, const float4& cmk,
                                             int base, const float4& w) {
    float pj = 0.f;
    #pragma unroll
    for (int m = 0; m < MM; ++m) {
        const int flat = J * MM + m;
        const int k = flat >> 2, c = flat & 3;
        const float mk = __shfl(getf(cmk, c), base + 9 + k, 64);
        pj += mk * (src[m].x * w.x + src[m].y * w.y + src[m].z * w.z + src[m].w * w.w);
    }
    return pj;
}

__global__ __launch_bounds__(256) void sg_dot_kernel(
    const int*   __restrict__ data,       // [B,12]
    const int*   __restrict__ c2m,        // [B,36]
    const float* __restrict__ c2m_mask,   // [B,36]
    const float* __restrict__ emb1,       // [V,128]
    const float* __restrict__ wbuf,       // [B,128]
    float*       __restrict__ out,
    int B)
{
    const int lane  = threadIdx.x & 63;
    const int wid   = threadIdx.x >> 6;
    const int sub   = lane >> 5;
    const int slane = lane & 31;
    const int base  = lane & 32;
    const int b     = blockIdx.x * RPB + wid * RPW + sub;

    float loss = 0.0f;

    if (b < B) {
        int4   ci  = {0, 0, 0, 0};
        float4 cmk = {0.f, 0.f, 0.f, 0.f};
        int    nm  = 0;
        if (slane < 9)       ci  = reinterpret_cast<const int4*>(c2m + (size_t)b * 36)[slane];
        else if (slane < 18) cmk = reinterpret_cast<const float4*>(c2m_mask + (size_t)b * 36)[slane - 9];
        if (slane < NEG)     nm  = data[(size_t)b * DROW + 2 + NEG + slane];

        float nmf[NEG];
        #pragma unroll
        for (int n = 0; n < NEG; ++n)
            nmf[n] = (float)__shfl(nm, base + n, 64);

        const int d0 = slane * 4;
        const float4 w = *reinterpret_cast<const float4*>(wbuf + (size_t)b * DD + d0);

        float4 A[MM], Bv[MM], C[MM];
        issue_ctx<0>(A,  ci, base, emb1, d0);
        issue_ctx<1>(Bv, ci, base, emb1, d0);
        issue_ctx<2>(C,  ci, base, emb1, d0);
        SB();

        float p[NCTX];
        p[0] = consume_dot<0>(A,  cmk, base, w);  issue_ctx<3>(A,  ci, base, emb1, d0); SB();
        p[1] = consume_dot<1>(Bv, cmk, base, w);  issue_ctx<4>(Bv, ci, base, emb1, d0); SB();
        p[2] = consume_dot<2>(C,  cmk, base, w);  issue_ctx<5>(C,  ci, base, emb1, d0); SB();
        p[3] = consume_dot<3>(A,  cmk, base, w);
        p[4] = consume_dot<4>(Bv, cmk, base, w);
        p[5] = consume_dot<5>(C,  cmk, base, w);

        #pragma unroll
        for (int j = 0; j < NCTX; ++j) {
            float v = p[j];
            #pragma unroll
            for (int off = 16; off >= 1; off >>= 1)
                v += __shfl_xor(v, off, 64);
            p[j] = v;
        }

        if (slane == 0) {
            float x = fminf(fmaxf(p[0], -10.0f), 10.0f);
            loss = log1pf(expf(-x));
            #pragma unroll
            for (int n = 0; n < NEG; ++n) {
                float y = fminf(fmaxf(-p[1 + n], -10.0f), 10.0f);
                loss += log1pf(expf(-y)) * nmf[n];
            }
        }
    }

    __shared__ float sacc[RPB];
    if (slane == 0) sacc[wid * RPW + sub] = loss;
    __syncthreads();
    if (threadIdx.x == 0) {
        float s = 0.0f;
        #pragma unroll
        for (int i = 0; i < RPB; ++i) s += sacc[i];
        atomicAdd(out, s);
    }
}

// ================= Fallback: fused single kernel (R5) =================
__global__ __launch_bounds__(256) void sg_fused_kernel(
    const int*   __restrict__ data,
    const int*   __restrict__ w2m,
    const float* __restrict__ w2m_mask,
    const int*   __restrict__ c2m,
    const float* __restrict__ c2m_mask,
    const float* __restrict__ emb0,
    const float* __restrict__ emb1,
    float*       __restrict__ out,
    int B)
{
    const int lane  = threadIdx.x & 63;
    const int wid   = threadIdx.x >> 6;
    const int sub   = lane >> 5;
    const int slane = lane & 31;
    const int base  = lane & 32;
    const int b     = blockIdx.x * RPB + wid * RPW + sub;

    float loss = 0.0f;
    if (b < B) {
        int4 ci = {0,0,0,0}; float4 cmk = {0.f,0.f,0.f,0.f};
        int wi = 0; float wmk = 0.f; int nm = 0;
        if (slane < 9)       ci  = reinterpret_cast<const int4*>(c2m + (size_t)b * 36)[slane];
        else if (slane < 18) cmk = reinterpret_cast<const float4*>(c2m_mask + (size_t)b * 36)[slane - 9];
        else if (slane < 24) wi  = w2m[(size_t)b * MM + (slane - 18)];
        else if (slane < 30) wmk = w2m_mask[(size_t)b * MM + (slane - 24)];
        if (slane < NEG) nm = data[(size_t)b * DROW + 2 + NEG + slane];

        float nmf[NEG];
        #pragma unroll
        for (int n = 0; n < NEG; ++n) nmf[n] = (float)__shfl(nm, base + n, 64);

        const int d0 = slane * 4;
        float4 wr[MM];
        #pragma unroll
        for (int m = 0; m < MM; ++m) {
            const int idx = __shfl(wi, base + 18 + m, 64);
            wr[m] = *reinterpret_cast<const float4*>(emb0 + (size_t)idx * DD + d0);
        }
        float4 A[MM], Bv[MM], C[MM];
        issue_ctx<0>(A, ci, base, emb1, d0);
        issue_ctx<1>(Bv, ci, base, emb1, d0);
        SB();
        float4 w = {0.f,0.f,0.f,0.f};
        #pragma unroll
        for (int m = 0; m < MM; ++m) {
            const float mk = __shfl(wmk, base + 24 + m, 64);
            w.x += wr[m].x * mk; w.y += wr[m].y * mk;
            w.z += wr[m].z * mk; w.w += wr[m].w * mk;
        }
        issue_ctx<2>(C, ci, base, emb1, d0);
        SB();
        float p[NCTX];
        p[0] = consume_dot<0>(A,  cmk, base, w);  issue_ctx<3>(A,  ci, base, emb1, d0); SB();
        p[1] = consume_dot<1>(Bv, cmk, base, w);  issue_ctx<4>(Bv, ci, base, emb1, d0); SB();
        p[2] = consume_dot<2>(C,  cmk, base, w);  issue_ctx<5>(C,  ci, base, emb1, d0); SB();
        p[3] = consume_dot<3>(A,  cmk, base, w);
        p[4] = consume_dot<4>(Bv, cmk, base, w);
        p[5] = consume_dot<5>(C,  cmk, base, w);

        #pragma unroll
        for (int j = 0; j < NCTX; ++j) {
            float v = p[j];
            #pragma unroll
            for (int off = 16; off >= 1; off >>= 1) v += __shfl_xor(v, off, 64);
            p[j] = v;
        }
        if (slane == 0) {
            float x = fminf(fmaxf(p[0], -10.0f), 10.0f);
            loss = log1pf(expf(-x));
            #pragma unroll
            for (int n = 0; n < NEG; ++n) {
                float y = fminf(fmaxf(-p[1 + n], -10.0f), 10.0f);
                loss += log1pf(expf(-y)) * nmf[n];
            }
        }
    }
    __shared__ float sacc[RPB];
    if (slane == 0) sacc[wid * RPW + sub] = loss;
    __syncthreads();
    if (threadIdx.x == 0) {
        float s = 0.0f;
        #pragma unroll
        for (int i = 0; i < RPB; ++i) s += sacc[i];
        atomicAdd(out, s);
    }
}

extern "C" void kernel_launch(void* const* d_in, const int* in_sizes, int n_in,
                              void* d_out, int out_size, void* d_ws, size_t ws_size,
                              hipStream_t stream) {
    const int*   data     = (const int*)  d_in[0];
    const int*   w2m      = (const int*)  d_in[1];
    const float* w2m_mask = (const float*)d_in[2];
    const int*   c2m      = (const int*)  d_in[3];
    const float* c2m_mask = (const float*)d_in[4];
    const float* emb0     = (const float*)d_in[5];
    const float* emb1     = (const float*)d_in[6];
    float* out = (float*)d_out;

    const int B = in_sizes[1] / MM;
    const int blocks = (B + RPB - 1) / RPB;

    hipMemsetAsync(out, 0, sizeof(float), stream);

    const size_t need = (size_t)B * DD * sizeof(float);
    if (ws_size >= need) {
        float* wbuf = (float*)d_ws;
        sg_w_kernel<<<blocks, 64 * WPB, 0, stream>>>(w2m, w2m_mask, emb0, wbuf, B);
        sg_dot_kernel<<<blocks, 64 * WPB, 0, stream>>>(data, c2m, c2m_mask, emb1, wbuf, out, B);
    } else {
        sg_fused_kernel<<<blocks, 64 * WPB, 0, stream>>>(
            data, w2m, w2m_mask, c2m, c2m_mask, emb0, emb1, out, B);
    }
}

// Round 8
// 97.539 us; speedup vs baseline: 1.2106x; 1.2106x over previous
//
#include <hip/hip_runtime.h>

#define NEG 5
#define MM 6
#define NCTX 6
#define DD 128
#define WPB 4           // waves per block
#define RPW 2           // rows per wave (half-wave per row)
#define RPB (WPB * RPW)
#define DROW 12
#define S_SCALE 4096.0f
#define INV_S (1.0f / 4096.0f)

#define SB() __builtin_amdgcn_sched_barrier(0)

typedef float v2f __attribute__((ext_vector_type(2)));

__device__ __forceinline__ int geti(const int4& v, int c) {
    switch (c) { case 0: return v.x; case 1: return v.y; case 2: return v.z; default: return v.w; }
}
__device__ __forceinline__ float getf(const float4& v, int c) {
    switch (c) { case 0: return v.x; case 1: return v.y; case 2: return v.z; default: return v.w; }
}

// ============ emb1 fp32 -> fp8(e4m3, x4096) conversion ============
__global__ __launch_bounds__(256) void cvt_fp8_kernel(
    const float* __restrict__ emb1, unsigned int* __restrict__ q, long n4)
{
    long i = (long)blockIdx.x * 256 + threadIdx.x;
    if (i >= n4) return;
    float4 v = reinterpret_cast<const float4*>(emb1)[i];
    int r = 0;
    r = __builtin_amdgcn_cvt_pk_fp8_f32(v.x * S_SCALE, v.y * S_SCALE, r, false);
    r = __builtin_amdgcn_cvt_pk_fp8_f32(v.z * S_SCALE, v.w * S_SCALE, r, true);
    q[i] = (unsigned int)r;
}

// ============ fp8 ctx gather/dot helpers ============
template<int J>
__device__ __forceinline__ void issue_ctx8(unsigned int* dst, const int4& ci, int base,
                                           const unsigned int* __restrict__ q, int sl) {
    #pragma unroll
    for (int m = 0; m < MM; ++m) {
        const int flat = J * MM + m;
        const int k = flat >> 2, c = flat & 3;
        const int idx = __shfl(geti(ci, c), base + k, 64);
        dst[m] = q[(size_t)idx * 32 + sl];
    }
}

template<int J>
__device__ __forceinline__ float consume_dot8(const unsigned int* src, const float4& cmk,
                                              int base, const float4& w) {
    float pj = 0.f;
    #pragma unroll
    for (int m = 0; m < MM; ++m) {
        const int flat = J * MM + m;
        const int k = flat >> 2, c = flat & 3;
        const float mk = __shfl(getf(cmk, c), base + 9 + k, 64);
        v2f lo = __builtin_amdgcn_cvt_pk_f32_fp8(src[m], false);
        v2f hi = __builtin_amdgcn_cvt_pk_f32_fp8(src[m], true);
        pj += mk * (lo[0] * w.x + lo[1] * w.y + hi[0] * w.z + hi[1] * w.w);
    }
    return pj * INV_S;
}

// fp32 fallback helpers (R5)
template<int J>
__device__ __forceinline__ void issue_ctx(float4* dst, const int4& ci, int base,
                                          const float* __restrict__ emb1, int d0) {
    #pragma unroll
    for (int m = 0; m < MM; ++m) {
        const int flat = J * MM + m;
        const int k = flat >> 2, c = flat & 3;
        const int idx = __shfl(geti(ci, c), base + k, 64);
        dst[m] = *reinterpret_cast<const float4*>(emb1 + (size_t)idx * DD + d0);
    }
}
template<int J>
__device__ __forceinline__ float consume_dot(const float4* src, const float4& cmk,
                                             int base, const float4& w) {
    float pj = 0.f;
    #pragma unroll
    for (int m = 0; m < MM; ++m) {
        const int flat = J * MM + m;
        const int k = flat >> 2, c = flat & 3;
        const float mk = __shfl(getf(cmk, c), base + 9 + k, 64);
        pj += mk * (src[m].x * w.x + src[m].y * w.y + src[m].z * w.z + src[m].w * w.w);
    }
    return pj;
}

// ============ fused kernel, fp8 emb1 path ============
__global__ __launch_bounds__(256) void sg_fused8_kernel(
    const int*   __restrict__ data,
    const int*   __restrict__ w2m,
    const float* __restrict__ w2m_mask,
    const int*   __restrict__ c2m,
    const float* __restrict__ c2m_mask,
    const float* __restrict__ emb0,
    const unsigned int* __restrict__ q,   // emb1 fp8, 32 uints/row
    float*       __restrict__ out,
    int B)
{
    const int lane  = threadIdx.x & 63;
    const int wid   = threadIdx.x >> 6;
    const int sub   = lane >> 5;
    const int slane = lane & 31;
    const int base  = lane & 32;
    const int b     = blockIdx.x * RPB + wid * RPW + sub;

    float loss = 0.0f;
    if (b < B) {
        int4 ci = {0,0,0,0}; float4 cmk = {0.f,0.f,0.f,0.f};
        int wi = 0; float wmk = 0.f; int nm = 0;
        if (slane < 9)       ci  = reinterpret_cast<const int4*>(c2m + (size_t)b * 36)[slane];
        else if (slane < 18) cmk = reinterpret_cast<const float4*>(c2m_mask + (size_t)b * 36)[slane - 9];
        else if (slane < 24) wi  = w2m[(size_t)b * MM + (slane - 18)];
        else if (slane < 30) wmk = w2m_mask[(size_t)b * MM + (slane - 24)];
        if (slane < NEG) nm = data[(size_t)b * DROW + 2 + NEG + slane];

        float nmf[NEG];
        #pragma unroll
        for (int n = 0; n < NEG; ++n) nmf[n] = (float)__shfl(nm, base + n, 64);

        const int d0 = slane * 4;

        // word gathers (fp32 emb0) + all 6 fp8 ctx bufs in flight
        float4 wr[MM];
        #pragma unroll
        for (int m = 0; m < MM; ++m) {
            const int idx = __shfl(wi, base + 18 + m, 64);
            wr[m] = *reinterpret_cast<const float4*>(emb0 + (size_t)idx * DD + d0);
        }
        unsigned int A8[MM], B8[MM], C8[MM], D8[MM], E8[MM], F8[MM];
        issue_ctx8<0>(A8, ci, base, q, slane);
        issue_ctx8<1>(B8, ci, base, q, slane);
        issue_ctx8<2>(C8, ci, base, q, slane);
        issue_ctx8<3>(D8, ci, base, q, slane);
        issue_ctx8<4>(E8, ci, base, q, slane);
        issue_ctx8<5>(F8, ci, base, q, slane);
        SB();

        float4 w = {0.f,0.f,0.f,0.f};
        #pragma unroll
        for (int m = 0; m < MM; ++m) {
            const float mk = __shfl(wmk, base + 24 + m, 64);
            w.x += wr[m].x * mk; w.y += wr[m].y * mk;
            w.z += wr[m].z * mk; w.w += wr[m].w * mk;
        }

        float p[NCTX];
        p[0] = consume_dot8<0>(A8, cmk, base, w);
        p[1] = consume_dot8<1>(B8, cmk, base, w);
        p[2] = consume_dot8<2>(C8, cmk, base, w);
        p[3] = consume_dot8<3>(D8, cmk, base, w);
        p[4] = consume_dot8<4>(E8, cmk, base, w);
        p[5] = consume_dot8<5>(F8, cmk, base, w);

        #pragma unroll
        for (int j = 0; j < NCTX; ++j) {
            float v = p[j];
            #pragma unroll
            for (int off = 16; off >= 1; off >>= 1) v += __shfl_xor(v, off, 64);
            p[j] = v;
        }
        if (slane == 0) {
            float x = fminf(fmaxf(p[0], -10.0f), 10.0f);
            loss = log1pf(expf(-x));
            #pragma unroll
            for (int n = 0; n < NEG; ++n) {
                float y = fminf(fmaxf(-p[1 + n], -10.0f), 10.0f);
                loss += log1pf(expf(-y)) * nmf[n];
            }
        }
    }
    __shared__ float sacc[RPB];
    if (slane == 0) sacc[wid * RPW + sub] = loss;
    __syncthreads();
    if (threadIdx.x == 0) {
        float s = 0.0f;
        #pragma unroll
        for (int i = 0; i < RPB; ++i) s += sacc[i];
        atomicAdd(out, s);
    }
}

// ============ fp32 fused fallback (R5) ============
__global__ __launch_bounds__(256) void sg_fused_kernel(
    const int*   __restrict__ data,
    const int*   __restrict__ w2m,
    const float* __restrict__ w2m_mask,
    const int*   __restrict__ c2m,
    const float* __restrict__ c2m_mask,
    const float* __restrict__ emb0,
    const float* __restrict__ emb1,
    float*       __restrict__ out,
    int B)
{
    const int lane  = threadIdx.x & 63;
    const int wid   = threadIdx.x >> 6;
    const int sub   = lane >> 5;
    const int slane = lane & 31;
    const int base  = lane & 32;
    const int b     = blockIdx.x * RPB + wid * RPW + sub;

    float loss = 0.0f;
    if (b < B) {
        int4 ci = {0,0,0,0}; float4 cmk = {0.f,0.f,0.f,0.f};
        int wi = 0; float wmk = 0.f; int nm = 0;
        if (slane < 9)       ci  = reinterpret_cast<const int4*>(c2m + (size_t)b * 36)[slane];
        else if (slane < 18) cmk = reinterpret_cast<const float4*>(c2m_mask + (size_t)b * 36)[slane - 9];
        else if (slane < 24) wi  = w2m[(size_t)b * MM + (slane - 18)];
        else if (slane < 30) wmk = w2m_mask[(size_t)b * MM + (slane - 24)];
        if (slane < NEG) nm = data[(size_t)b * DROW + 2 + NEG + slane];

        float nmf[NEG];
        #pragma unroll
        for (int n = 0; n < NEG; ++n) nmf[n] = (float)__shfl(nm, base + n, 64);

        const int d0 = slane * 4;
        float4 wr[MM];
        #pragma unroll
        for (int m = 0; m < MM; ++m) {
            const int idx = __shfl(wi, base + 18 + m, 64);
            wr[m] = *reinterpret_cast<const float4*>(emb0 + (size_t)idx * DD + d0);
        }
        float4 A[MM], Bv[MM], C[MM];
        issue_ctx<0>(A, ci, base, emb1, d0);
        issue_ctx<1>(Bv, ci, base, emb1, d0);
        SB();
        float4 w = {0.f,0.f,0.f,0.f};
        #pragma unroll
        for (int m = 0; m < MM; ++m) {
            const float mk = __shfl(wmk, base + 24 + m, 64);
            w.x += wr[m].x * mk; w.y += wr[m].y * mk;
            w.z += wr[m].z * mk; w.w += wr[m].w * mk;
        }
        issue_ctx<2>(C, ci, base, emb1, d0);
        SB();
        float p[NCTX];
        p[0] = consume_dot<0>(A,  cmk, base, w);  issue_ctx<3>(A,  ci, base, emb1, d0); SB();
        p[1] = consume_dot<1>(Bv, cmk, base, w);  issue_ctx<4>(Bv, ci, base, emb1, d0); SB();
        p[2] = consume_dot<2>(C,  cmk, base, w);  issue_ctx<5>(C,  ci, base, emb1, d0); SB();
        p[3] = consume_dot<3>(A,  cmk, base, w);
        p[4] = consume_dot<4>(Bv, cmk, base, w);
        p[5] = consume_dot<5>(C,  cmk, base, w);

        #pragma unroll
        for (int j = 0; j < NCTX; ++j) {
            float v = p[j];
            #pragma unroll
            for (int off = 16; off >= 1; off >>= 1) v += __shfl_xor(v, off, 64);
            p[j] = v;
        }
        if (slane == 0) {
            float x = fminf(fmaxf(p[0], -10.0f), 10.0f);
            loss = log1pf(expf(-x));
            #pragma unroll
            for (int n = 0; n < NEG; ++n) {
                float y = fminf(fmaxf(-p[1 + n], -10.0f), 10.0f);
                loss += log1pf(expf(-y)) * nmf[n];
            }
        }
    }
    __shared__ float sacc[RPB];
    if (slane == 0) sacc[wid * RPW + sub] = loss;
    __syncthreads();
    if (threadIdx.x == 0) {
        float s = 0.0f;
        #pragma unroll
        for (int i = 0; i < RPB; ++i) s += sacc[i];
        atomicAdd(out, s);
    }
}

extern "C" void kernel_launch(void* const* d_in, const int* in_sizes, int n_in,
                              void* d_out, int out_size, void* d_ws, size_t ws_size,
                              hipStream_t stream) {
    const int*   data     = (const int*)  d_in[0];
    const int*   w2m      = (const int*)  d_in[1];
    const float* w2m_mask = (const float*)d_in[2];
    const int*   c2m      = (const int*)  d_in[3];
    const float* c2m_mask = (const float*)d_in[4];
    const float* emb0     = (const float*)d_in[5];
    const float* emb1     = (const float*)d_in[6];
    float* out = (float*)d_out;

    const int B     = in_sizes[1] / MM;       // word2morph has B*6 elements
    const int vocab = in_sizes[6] / DD;       // emb1 rows
    const int blocks = (B + RPB - 1) / RPB;

    (void)hipMemsetAsync(out, 0, sizeof(float), stream);

    const size_t need = (size_t)vocab * DD;   // 1 byte per element
    if (ws_size >= need) {
        unsigned int* q = (unsigned int*)d_ws;
        const long n4 = (long)vocab * 32;     // uints in fp8 table
        const long cvt_blocks = (n4 + 255) / 256;
        cvt_fp8_kernel<<<(int)cvt_blocks, 256, 0, stream>>>(emb1, q, n4);
        sg_fused8_kernel<<<blocks, 64 * WPB, 0, stream>>>(
            data, w2m, w2m_mask, c2m, c2m_mask, emb0, q, out, B);
    } else {
        sg_fused_kernel<<<blocks, 64 * WPB, 0, stream>>>(
            data, w2m, w2m_mask, c2m, c2m_mask, emb0, emb1, out, B);
    }
}